// Round 1
// baseline (3363.200 us; speedup 1.0000x reference)
//
#include <hip/hip_runtime.h>
#include <math.h>

// BasicRecurrentEntityEncoder: B=256, S=64, L=16, D=256, K=30
// One block per batch element; 256 threads = one output dim each.
// Scan state h kept (a) transposed in LDS for the h@U matvec broadcast,
// (b) sliced per-thread in registers for gate/update/norm.

constexpr int Sc  = 64;
constexpr int Lc  = 16;
constexpr int Dc  = 256;
constexpr int Kc  = 30;
constexpr int TPB = 256;
constexpr int HST = 36;   // h row stride in floats: 144B, 16B-aligned, (4t+k)%32 banks

__device__ __forceinline__ float allreduce64(float v) {
    v += __shfl_xor(v, 1, 64);
    v += __shfl_xor(v, 2, 64);
    v += __shfl_xor(v, 4, 64);
    v += __shfl_xor(v, 8, 64);
    v += __shfl_xor(v, 16, 64);
    v += __shfl_xor(v, 32, 64);
    return v;
}

__global__ __launch_bounds__(TPB, 1)
void entity_scan(const int* __restrict__ prgrph,
                 const unsigned char* __restrict__ pmask8,
                 const int* __restrict__ pmask32,
                 const float* __restrict__ keys,
                 const float* __restrict__ emb,
                 const float* __restrict__ U,
                 const float* __restrict__ V,
                 const float* __restrict__ W,
                 float* __restrict__ out,
                 float* __restrict__ enc_ws,   // [B][S][D] f32 scratch
                 float* __restrict__ eW_ws)    // [B][S][D] f32 scratch
{
    const int b    = blockIdx.x;
    const int t    = threadIdx.x;
    const int wave = t >> 6;
    const int lane = t & 63;

    __shared__ __align__(16) float hL[Dc * HST];  // hL[d*HST + k] = h[k][d]
    __shared__ float sg[4][32];                   // gate partial sums per wave
    __shared__ float ssc[4][32];                  // sumsq partials per wave
    __shared__ unsigned int mbits[Sc];
    __shared__ unsigned char maskL[Sc];

    // ---- detect mask storage: bool-as-byte vs int32 (uniform across grid) ----
    int probe;
    {
        const unsigned char* p = pmask8 + 4 * t;  // first 1024 bytes, safe in both modes
        probe = (int)(p[1] | p[2] | p[3]);
    }
    const bool bytemode = (__syncthreads_or(probe) != 0);

    // ---- pack this block's word masks into per-sentence bitmasks ----
    if (t < Sc) {
        unsigned bits = 0;
        const int base = (b * Sc + t) * Lc;
        if (bytemode) {
            for (int l = 0; l < Lc; ++l) if (pmask8[base + l]) bits |= (1u << l);
        } else {
            for (int l = 0; l < Lc; ++l) if (pmask32[base + l]) bits |= (1u << l);
        }
        mbits[t] = bits;
        maskL[t] = (bits != 0) ? (unsigned char)1 : (unsigned char)0;
    }
    __syncthreads();

    // ---- prologue 1: sentence encodings  enc[r][t] = sum_l mask * emb[tok][t] ----
    const int* tok_b = prgrph + b * (Sc * Lc);
    float* enc_b = enc_ws + (size_t)b * (Sc * Dc);
    for (int r = 0; r < Sc; ++r) {
        const unsigned bits = mbits[r];
        float acc = 0.f;
        for (int l = 0; l < Lc; ++l) {
            if ((bits >> l) & 1u) {
                int tokv = tok_b[r * Lc + l];
                acc += emb[(size_t)tokv * Dc + t];
            }
        }
        enc_b[r * Dc + t] = acc;
    }

    // ---- prologue 2: per-thread keys slice + keysV = keys @ V (step-invariant) ----
    const float* keys_b = keys + (size_t)b * (Kc * Dc);
    float keysr[Kc], kv[Kc];
#pragma unroll
    for (int k = 0; k < Kc; ++k) keysr[k] = keys_b[k * Dc + t];
#pragma unroll
    for (int k = 0; k < Kc; ++k) kv[k] = 0.f;
    {
        const float* Vcol = V + t;
#pragma unroll 1
        for (int j = 0; j < Dc; ++j) {
            float vj = Vcol[j * Dc];
#pragma unroll
            for (int k = 0; k < Kc; ++k) kv[k] += keys_b[k * Dc + j] * vj;
        }
    }

    // ---- prologue 3: eW = enc @ W for all 64 sentences ----
    __syncthreads();  // enc writes (all threads) must be visible before cross-dim reads
    {
        float acc[Sc];
#pragma unroll
        for (int r = 0; r < Sc; ++r) acc[r] = 0.f;
        const float* Wcol = W + t;
#pragma unroll 1
        for (int j = 0; j < Dc; ++j) {
            float wj = Wcol[j * Dc];
#pragma unroll
            for (int r = 0; r < Sc; ++r) acc[r] += enc_b[r * Dc + j] * wj;
        }
        float* eW_b = eW_ws + (size_t)b * (Sc * Dc);
#pragma unroll
        for (int r = 0; r < Sc; ++r) eW_b[r * Dc + t] = acc[r];
    }

    // ---- init h = 0 ----
    float hreg[Kc];
#pragma unroll
    for (int k = 0; k < Kc; ++k) hreg[k] = 0.f;
    {
        float4 z = make_float4(0.f, 0.f, 0.f, 0.f);
        float4* hp = (float4*)&hL[t * HST];
#pragma unroll
        for (int g = 0; g < 8; ++g) hp[g] = z;
    }
    __syncthreads();

    // ---- the scan ----
    const float* Ucol = U + t;
    const float* eW_b = eW_ws + (size_t)b * (Sc * Dc);
#pragma unroll 1
    for (int s = 0; s < Sc; ++s) {
        if (!maskL[s]) continue;  // block-uniform: whole step is a no-op
        const float e  = enc_b[s * Dc + t];
        const float ew = eW_b[s * Dc + t];

        // gate partials: p_k = sum_d e_d * (h[k][d] + keys[k][d])
#pragma unroll
        for (int k = 0; k < Kc; ++k) {
            float p = e * (hreg[k] + keysr[k]);
            p = allreduce64(p);
            if (lane == 0) sg[wave][k] = p;
        }
        __syncthreads();

        // matvec: y[k] = sum_j h[k][j] * U[j][t]   (h broadcast from LDS, U from L2)
        float y[Kc];
#pragma unroll
        for (int k = 0; k < Kc; ++k) y[k] = 0.f;
#pragma unroll 2
        for (int j = 0; j < Dc; ++j) {
            const float uj = Ucol[j * Dc];
            const float4* hrow = (const float4*)&hL[j * HST];
            float ha[32];
#pragma unroll
            for (int g = 0; g < 8; ++g) *(float4*)(&ha[4 * g]) = hrow[g];
#pragma unroll
            for (int k = 0; k < Kc; ++k) y[k] += ha[k] * uj;
        }

        // update: u = h + g * relu(y + keysV + eW); sumsq partials
        float u[Kc];
#pragma unroll
        for (int k = 0; k < Kc; ++k) {
            float gk = sg[0][k] + sg[1][k] + sg[2][k] + sg[3][k];
            gk = 1.f / (1.f + expf(-gk));
            float ht = y[k] + kv[k] + ew;
            ht = ht > 0.f ? ht : 0.f;
            float uv = hreg[k] + gk * ht;
            u[k] = uv;
            float ss = allreduce64(uv * uv);
            if (lane == 0) ssc[wave][k] = ss;
        }
        __syncthreads();  // all matvec reads of hL done + ssc ready

        // l2-normalize and publish new h
#pragma unroll
        for (int k = 0; k < Kc; ++k) {
            float tot = ssc[0][k] + ssc[1][k] + ssc[2][k] + ssc[3][k];
            tot = fmaxf(tot, 1e-12f);
            float rs = rsqrtf(tot);
            rs = rs * (1.5f - 0.5f * tot * rs * rs);  // one Newton step
            hreg[k] = u[k] * rs;
        }
        {
            float hv[32];
#pragma unroll
            for (int k = 0; k < 32; ++k) hv[k] = (k < Kc) ? hreg[k] : 0.f;
            float4* hp = (float4*)&hL[t * HST];
#pragma unroll
            for (int g = 0; g < 8; ++g) hp[g] = *(float4*)(&hv[4 * g]);
        }
        __syncthreads();  // hL fully updated before next step's matvec
    }

    // ---- epilogue: write final h ----
    float* out_b = out + (size_t)b * (Kc * Dc);
#pragma unroll
    for (int k = 0; k < Kc; ++k) out_b[k * Dc + t] = hreg[k];
}

extern "C" void kernel_launch(void* const* d_in, const int* in_sizes, int n_in,
                              void* d_out, int out_size, void* d_ws, size_t ws_size,
                              hipStream_t stream) {
    const int*   prgrph = (const int*)d_in[0];
    const void*  pmask  = d_in[1];
    const float* keys   = (const float*)d_in[2];
    const float* emb    = (const float*)d_in[3];
    const float* U      = (const float*)d_in[4];
    const float* V      = (const float*)d_in[5];
    const float* W      = (const float*)d_in[6];

    const int B = in_sizes[2] / (Kc * Dc);   // keys is [B,K,D]

    float* enc_ws = (float*)d_ws;                          // B*S*D f32
    float* eWp    = enc_ws + (size_t)B * Sc * Dc;          // B*S*D f32

    entity_scan<<<B, TPB, 0, stream>>>(prgrph,
                                       (const unsigned char*)pmask,
                                       (const int*)pmask,
                                       keys, emb, U, V, W,
                                       (float*)d_out, enc_ws, eWp);
}

// Round 2
// 924.569 us; speedup vs baseline: 3.6376x; 3.6376x over previous
//
#include <hip/hip_runtime.h>
#include <math.h>

// BasicRecurrentEntityEncoder: B=256, S=64, L=16, D=256, K=30
// MFMA (bf16x2 split, 4-product) for h@U / keys@V / enc@W.
// One block per batch; 4 waves; LDS: A1|A2 bf16 split planes [32][256] + C f32 [32][256] = 64KB.
// B-operands (U^T,V^T,W^T) pre-split+packed in fragment order by pack_planes.

constexpr int Sc = 64, Lc = 16, Dc = 256, Kc = 30, TPB = 256;

typedef short s8v __attribute__((ext_vector_type(8)));
typedef short s4v __attribute__((ext_vector_type(4)));
typedef float f4v __attribute__((ext_vector_type(4)));

__device__ __forceinline__ short f2bf(float x) {  // RNE float->bf16 (finite inputs)
    unsigned u = __float_as_uint(x);
    u = u + 0x7FFFu + ((u >> 16) & 1u);
    return (short)(u >> 16);
}
__device__ __forceinline__ float bf2f(short s) {
    return __uint_as_float(((unsigned)(unsigned short)s) << 16);
}
__device__ __forceinline__ float allreduce64(float v) {
    v += __shfl_xor(v, 1, 64);  v += __shfl_xor(v, 2, 64);  v += __shfl_xor(v, 4, 64);
    v += __shfl_xor(v, 8, 64);  v += __shfl_xor(v, 16, 64); v += __shfl_xor(v, 32, 64);
    return v;
}

// ---- pack U,V,W into bf16-split planes in MFMA-B fragment order ----
// plane layout: [kt(8)][ntg(16)][lane(64)][elem(8)] ; elem i <-> logical k = 32*kt + 8*(l>>4) + i
// logical n = 16*ntg + (l&15).  Per-wave loads become sequential 1KB bursts.
__global__ void pack_planes(const float* __restrict__ U, const float* __restrict__ V,
                            const float* __restrict__ W, short* __restrict__ P) {
    int gid = blockIdx.x * blockDim.x + threadIdx.x;   // 3*8*16*64 = 24576
    int l = gid & 63, ntg = (gid >> 6) & 15, kt = (gid >> 10) & 7, mat = gid >> 13;
    const float* M = (mat == 0) ? U : ((mat == 1) ? V : W);
    short* P1 = P + (size_t)mat * 131072;
    short* P2 = P1 + 65536;
    int n  = ntg * 16 + (l & 15);
    int k0 = kt * 32 + (l >> 4) * 8;
    s8v hi, lo;
#pragma unroll
    for (int i = 0; i < 8; ++i) {
        float x = M[(size_t)(k0 + i) * Dc + n];
        short h = f2bf(x);
        hi[i] = h;
        lo[i] = f2bf(x - bf2f(h));
    }
    size_t idx = ((size_t)(kt * 16 + ntg) * 64 + l) * 8;
    *(s8v*)(P1 + idx) = hi;
    *(s8v*)(P2 + idx) = lo;
}

// swizzled LDS accessors (XOR row bits into 16B-slot bits -> conflict-free frag reads)
__device__ __forceinline__ int aoff(int row, int kbyte) { return (row * 512 + kbyte) ^ ((row & 7) << 4); }
__device__ __forceinline__ int coff(int row, int cbyte) { return (row * 1024 + cbyte) ^ ((row & 7) << 4); }

__device__ __forceinline__ void store_split_row(short* A1s, short* A2s, int row, int l,
                                                float x0, float x1, float x2, float x3) {
    s4v hi, lo;
    short h0 = f2bf(x0); hi[0] = h0; lo[0] = f2bf(x0 - bf2f(h0));
    short h1 = f2bf(x1); hi[1] = h1; lo[1] = f2bf(x1 - bf2f(h1));
    short h2 = f2bf(x2); hi[2] = h2; lo[2] = f2bf(x2 - bf2f(h2));
    short h3 = f2bf(x3); hi[3] = h3; lo[3] = f2bf(x3 - bf2f(h3));
    int off = aoff(row, 8 * l);
    *(s4v*)((char*)A1s + off) = hi;
    *(s4v*)((char*)A2s + off) = lo;
}

// C[32][256] (f32, swizzled) = (A1+A2) @ (B1+B2) ; A planes in LDS, B planes packed global.
__device__ __forceinline__ void mfma_pass(const short* A1s, const short* A2s,
                                          const short* __restrict__ B1, const short* __restrict__ B2,
                                          char* Cb, int w, int l) {
    const int q = l >> 4, m = l & 15;
    f4v acc[2][4];
#pragma unroll
    for (int mt = 0; mt < 2; ++mt)
#pragma unroll
        for (int nt = 0; nt < 4; ++nt) { acc[mt][nt][0] = 0.f; acc[mt][nt][1] = 0.f; acc[mt][nt][2] = 0.f; acc[mt][nt][3] = 0.f; }
#pragma unroll
    for (int kt = 0; kt < 8; ++kt) {
        s8v a1[2], a2[2];
#pragma unroll
        for (int mt = 0; mt < 2; ++mt) {
            int off = aoff(16 * mt + m, 64 * kt + 16 * q);
            a1[mt] = *(const s8v*)((const char*)A1s + off);
            a2[mt] = *(const s8v*)((const char*)A2s + off);
        }
        s8v b1[4], b2[4];
#pragma unroll
        for (int nt = 0; nt < 4; ++nt) {
            size_t idx = ((size_t)(kt * 16 + 4 * w + nt) * 64 + l) * 8;
            b1[nt] = *(const s8v*)(B1 + idx);
            b2[nt] = *(const s8v*)(B2 + idx);
        }
#pragma unroll
        for (int mt = 0; mt < 2; ++mt)
#pragma unroll
            for (int nt = 0; nt < 4; ++nt) {
                acc[mt][nt] = __builtin_amdgcn_mfma_f32_16x16x32_bf16(a1[mt], b1[nt], acc[mt][nt], 0, 0, 0);
                acc[mt][nt] = __builtin_amdgcn_mfma_f32_16x16x32_bf16(a1[mt], b2[nt], acc[mt][nt], 0, 0, 0);
                acc[mt][nt] = __builtin_amdgcn_mfma_f32_16x16x32_bf16(a2[mt], b1[nt], acc[mt][nt], 0, 0, 0);
                acc[mt][nt] = __builtin_amdgcn_mfma_f32_16x16x32_bf16(a2[mt], b2[nt], acc[mt][nt], 0, 0, 0);
            }
    }
#pragma unroll
    for (int mt = 0; mt < 2; ++mt)
#pragma unroll
        for (int nt = 0; nt < 4; ++nt)
#pragma unroll
            for (int reg = 0; reg < 4; ++reg) {
                int row = 16 * mt + 4 * q + reg;
                int col = 64 * w + 16 * nt + m;
                *(float*)(Cb + coff(row, 4 * col)) = acc[mt][nt][reg];
            }
}

__global__ __launch_bounds__(TPB, 1)
void entity_mfma(const int* __restrict__ prgrph,
                 const unsigned char* __restrict__ pmask8,
                 const int* __restrict__ pmask32,
                 const float* __restrict__ keys,
                 const float* __restrict__ emb,
                 const short* __restrict__ UT1, const short* __restrict__ UT2,
                 const short* __restrict__ VT1, const short* __restrict__ VT2,
                 const short* __restrict__ WT1, const short* __restrict__ WT2,
                 float* __restrict__ out,
                 float* __restrict__ enc_ws,   // [B][S][D] f32
                 short* __restrict__ eW_ws)    // [B][S][D] bf16
{
    const int b = blockIdx.x, t = threadIdx.x;
    const int w = t >> 6, l = t & 63;

    __shared__ __align__(16) char lds[65536];
    short* A1s = (short*)lds;            // [32][256] bf16 hi plane (swizzled), 16KB
    short* A2s = (short*)(lds + 16384);  // lo plane, 16KB
    char*  Cb  = lds + 32768;            // [32][256] f32 (swizzled), 32KB
    unsigned* mbits = (unsigned*)(lds + 31 * 512);  // aliased in A1 row 31 (prologue only)

    // ---- mask storage probe (byte-bool vs int32) ----
    int probe;
    { const unsigned char* p = pmask8 + 4 * t; probe = (int)(p[1] | p[2] | p[3]); }
    const bool bytemode = (__syncthreads_or(probe) != 0);

    if (t < Sc) {
        unsigned bits = 0;
        const int base = (b * Sc + t) * Lc;
        if (bytemode) { for (int i = 0; i < Lc; ++i) if (pmask8[base + i])  bits |= 1u << i; }
        else          { for (int i = 0; i < Lc; ++i) if (pmask32[base + i]) bits |= 1u << i; }
        mbits[t] = bits;
    }
    __syncthreads();

    // ---- sentence encodings (thread t = dim column) ----
    const int* tok_b = prgrph + b * (Sc * Lc);
    float* enc_b = enc_ws + (size_t)b * (Sc * Dc);
    for (int r = 0; r < Sc; ++r) {
        unsigned bits = mbits[r];
        float acc = 0.f;
        for (int lw = 0; lw < Lc; ++lw)
            if ((bits >> lw) & 1u) acc += emb[(size_t)tok_b[r * Lc + lw] * Dc + t];
        enc_b[r * Dc + t] = acc;
    }
    unsigned long long mask64 = 0;
#pragma unroll 1
    for (int s2 = 0; s2 < Sc; ++s2)
        mask64 |= ((unsigned long long)(mbits[s2] != 0)) << s2;
    __syncthreads();   // enc visible; mbits dead (A1 row 31 free to clobber)

    // ---- hoist per-wave keys slice (rows 8w+r, dims 4l..4l+3) ----
    const float* keys_b = keys + (size_t)b * (Kc * Dc);
    float4 keysr[8];
#pragma unroll
    for (int r = 0; r < 8; ++r) {
        int row = 8 * w + r;
        keysr[r] = (row < Kc) ? *(const float4*)(keys_b + row * Dc + 4 * l)
                              : make_float4(0.f, 0.f, 0.f, 0.f);
    }

    short* eW_b = eW_ws + (size_t)b * (Sc * Dc);

    // ---- eW = enc @ W (two 32-row passes) ----
    for (int pass = 0; pass < 2; ++pass) {
#pragma unroll
        for (int r = 0; r < 8; ++r) {
            int row = 8 * w + r, sent = pass * 32 + row;
            float4 ev = *(const float4*)(enc_b + sent * Dc + 4 * l);
            store_split_row(A1s, A2s, row, l, ev.x, ev.y, ev.z, ev.w);
        }
        __syncthreads();
        mfma_pass(A1s, A2s, WT1, WT2, Cb, w, l);
        __syncthreads();
#pragma unroll
        for (int r = 0; r < 8; ++r) {
            int row = 8 * w + r, sent = pass * 32 + row;
            float4 yv = *(const float4*)(Cb + coff(row, 16 * l));
            s4v o; o[0] = f2bf(yv.x); o[1] = f2bf(yv.y); o[2] = f2bf(yv.z); o[3] = f2bf(yv.w);
            *(s4v*)(eW_b + sent * Dc + 4 * l) = o;
        }
        __syncthreads();
    }

    // ---- kv = keys @ V ----
#pragma unroll
    for (int r = 0; r < 8; ++r) {
        int row = 8 * w + r;
        store_split_row(A1s, A2s, row, l, keysr[r].x, keysr[r].y, keysr[r].z, keysr[r].w);
    }
    __syncthreads();
    mfma_pass(A1s, A2s, VT1, VT2, Cb, w, l);
    __syncthreads();
    float4 kvr[8];
#pragma unroll
    for (int r = 0; r < 8; ++r) {
        int row = 8 * w + r;
        kvr[r] = (row < Kc) ? *(const float4*)(Cb + coff(row, 16 * l))
                            : make_float4(0.f, 0.f, 0.f, 0.f);
    }
    __syncthreads();

    // ---- zero A planes + h ----
    {
        s8v z; 
#pragma unroll
        for (int i = 0; i < 8; ++i) z[i] = 0;
#pragma unroll
        for (int i = 0; i < 4; ++i) {
            *(s8v*)((char*)A1s + t * 64 + i * 16) = z;
            *(s8v*)((char*)A2s + t * 64 + i * 16) = z;
        }
    }
    float4 h[8];
#pragma unroll
    for (int r = 0; r < 8; ++r) h[r] = make_float4(0.f, 0.f, 0.f, 0.f);
    __syncthreads();

    // ---- the scan ----
#pragma unroll 1
    for (int s = 0; s < Sc; ++s) {
        if (!((mask64 >> s) & 1ull)) continue;

        mfma_pass(A1s, A2s, UT1, UT2, Cb, w, l);   // C = h @ U
        __syncthreads();

        float4 e4 = *(const float4*)(enc_b + s * Dc + 4 * l);
        float ew0, ew1, ew2, ew3;
        { s4v es = *(const s4v*)(eW_b + s * Dc + 4 * l);
          ew0 = bf2f(es[0]); ew1 = bf2f(es[1]); ew2 = bf2f(es[2]); ew3 = bf2f(es[3]); }

        float g[8];
#pragma unroll
        for (int r = 0; r < 8; ++r) {
            int row = 8 * w + r;
            if (row < Kc) {
                float p = e4.x * (h[r].x + keysr[r].x) + e4.y * (h[r].y + keysr[r].y)
                        + e4.z * (h[r].z + keysr[r].z) + e4.w * (h[r].w + keysr[r].w);
                p = allreduce64(p);
                g[r] = 1.f / (1.f + expf(-p));
            }
        }
#pragma unroll
        for (int r = 0; r < 8; ++r) {
            int row = 8 * w + r;
            if (row >= Kc) continue;
            float4 yv = *(const float4*)(Cb + coff(row, 16 * l));
            float t0 = yv.x + kvr[r].x + ew0; t0 = fmaxf(t0, 0.f);
            float t1 = yv.y + kvr[r].y + ew1; t1 = fmaxf(t1, 0.f);
            float t2 = yv.z + kvr[r].z + ew2; t2 = fmaxf(t2, 0.f);
            float t3 = yv.w + kvr[r].w + ew3; t3 = fmaxf(t3, 0.f);
            float u0 = h[r].x + g[r] * t0;
            float u1 = h[r].y + g[r] * t1;
            float u2 = h[r].z + g[r] * t2;
            float u3 = h[r].w + g[r] * t3;
            float ss = allreduce64(u0 * u0 + u1 * u1 + u2 * u2 + u3 * u3);
            ss = fmaxf(ss, 1e-12f);
            float rs = rsqrtf(ss);
            rs = rs * (1.5f - 0.5f * ss * rs * rs);   // Newton -> ~exact fp32 rsqrt
            u0 *= rs; u1 *= rs; u2 *= rs; u3 *= rs;
            h[r] = make_float4(u0, u1, u2, u3);
            store_split_row(A1s, A2s, row, l, u0, u1, u2, u3);
        }
        __syncthreads();
    }

    // ---- epilogue ----
    float* out_b = out + (size_t)b * (Kc * Dc);
#pragma unroll
    for (int r = 0; r < 8; ++r) {
        int row = 8 * w + r;
        if (row < Kc) *(float4*)(out_b + row * Dc + 4 * l) = h[r];
    }
}

extern "C" void kernel_launch(void* const* d_in, const int* in_sizes, int n_in,
                              void* d_out, int out_size, void* d_ws, size_t ws_size,
                              hipStream_t stream) {
    const int*   prgrph = (const int*)d_in[0];
    const void*  pmask  = d_in[1];
    const float* keys   = (const float*)d_in[2];
    const float* emb    = (const float*)d_in[3];
    const float* U      = (const float*)d_in[4];
    const float* V      = (const float*)d_in[5];
    const float* W      = (const float*)d_in[6];

    const int B = in_sizes[2] / (Kc * Dc);   // keys is [B,K,D]

    short* P      = (short*)d_ws;                                   // 6 planes x 65536 bf16 = 768KB
    float* enc_ws = (float*)((char*)d_ws + 786432);                 // B*S*D f32 = 16.8MB
    short* eW_ws  = (short*)((char*)d_ws + 786432 + (size_t)B * Sc * Dc * 4);  // B*S*D bf16 = 8.4MB

    pack_planes<<<96, 256, 0, stream>>>(U, V, W, P);
    entity_mfma<<<B, TPB, 0, stream>>>(prgrph,
                                       (const unsigned char*)pmask, (const int*)pmask,
                                       keys, emb,
                                       P, P + 65536, P + 131072, P + 196608, P + 262144, P + 327680,
                                       (float*)d_out, enc_ws, eW_ws);
}

// Round 3
// 890.214 us; speedup vs baseline: 3.7780x; 1.0386x over previous
//
#include <hip/hip_runtime.h>
#include <math.h>

// BasicRecurrentEntityEncoder: B=256, S=64, L=16, D=256, K=30
// Round 3: TPB=512 (2 waves/SIMD), 32x32x16 bf16 MFMA, 3-product bf16x2 split,
// B-operands (U/V/W hi+lo planes) held in 128 VGPRs per wave (zero global B
// traffic in the scan). A (h) split-planes + C in LDS, all accesses at bank floor.

constexpr int Sc = 64, Lc = 16, Dc = 256, Kc = 30, TPB = 512;

typedef short s8v  __attribute__((ext_vector_type(8)));
typedef short s4v  __attribute__((ext_vector_type(4)));
typedef float f4v  __attribute__((ext_vector_type(4)));
typedef float f16v __attribute__((ext_vector_type(16)));

__device__ __forceinline__ short f2bf(float x) {  // RNE float->bf16
    unsigned u = __float_as_uint(x);
    u = u + 0x7FFFu + ((u >> 16) & 1u);
    return (short)(u >> 16);
}
__device__ __forceinline__ float bf2f(short s) {
    return __uint_as_float(((unsigned)(unsigned short)s) << 16);
}
__device__ __forceinline__ float allreduce64(float v) {
    v += __shfl_xor(v, 1, 64);  v += __shfl_xor(v, 2, 64);  v += __shfl_xor(v, 4, 64);
    v += __shfl_xor(v, 8, 64);  v += __shfl_xor(v, 16, 64); v += __shfl_xor(v, 32, 64);
    return v;
}

// ---- pack U,V,W into bf16-split planes in 32x32x16 MFMA-B fragment order ----
// P[mat][plane][kt(16)][w(8)][lane(64)][elem(8)]
// logical k = 16*kt + 8*(l>>5) + elem ; logical n (col) = 32*w + (l&31)
__global__ void pack32(const float* __restrict__ U, const float* __restrict__ V,
                       const float* __restrict__ W, short* __restrict__ P) {
    int gid = blockIdx.x * blockDim.x + threadIdx.x;   // 3*16*8*64 = 24576
    int l = gid & 63, w = (gid >> 6) & 7, kt = (gid >> 9) & 15, mat = gid >> 13;
    const float* M = (mat == 0) ? U : ((mat == 1) ? V : W);
    short* P1 = P + (size_t)mat * 131072;
    short* P2 = P1 + 65536;
    int n  = 32 * w + (l & 31);
    int k0 = 16 * kt + 8 * (l >> 5);
    s8v hi, lo;
#pragma unroll
    for (int e = 0; e < 8; ++e) {
        float x = M[(size_t)(k0 + e) * Dc + n];
        short h = f2bf(x);
        hi[e] = h;
        lo[e] = f2bf(x - bf2f(h));
    }
    size_t idx = ((size_t)(kt * 8 + w) * 64 + l) * 8;
    *(s8v*)(P1 + idx) = hi;
    *(s8v*)(P2 + idx) = lo;
}

// swizzled LDS accessors (XOR row bits into 16B-slot bits -> bank-floor access)
__device__ __forceinline__ int aoff(int row, int kbyte) { return (row * 512 + kbyte) ^ ((row & 7) << 4); }
__device__ __forceinline__ int coff(int row, int cbyte) { return (row * 1024 + cbyte) ^ ((row & 7) << 4); }

__device__ __forceinline__ void store_split_row(char* A1s, char* A2s, int row, int l,
                                                float x0, float x1, float x2, float x3) {
    s4v hi, lo;
    short h0 = f2bf(x0); hi[0] = h0; lo[0] = f2bf(x0 - bf2f(h0));
    short h1 = f2bf(x1); hi[1] = h1; lo[1] = f2bf(x1 - bf2f(h1));
    short h2 = f2bf(x2); hi[2] = h2; lo[2] = f2bf(x2 - bf2f(h2));
    short h3 = f2bf(x3); hi[3] = h3; lo[3] = f2bf(x3 - bf2f(h3));
    int off = aoff(row, 8 * l);
    *(s4v*)(A1s + off) = hi;
    *(s4v*)(A2s + off) = lo;
}

// load one matrix's hi/lo B planes into registers (32 x b128, coalesced)
__device__ __forceinline__ void loadB(const short* __restrict__ P1, const short* __restrict__ P2,
                                      int w, int l, s8v (&b1)[16], s8v (&b2)[16]) {
#pragma unroll
    for (int kt = 0; kt < 16; ++kt) {
        size_t idx = ((size_t)(kt * 8 + w) * 64 + l) * 8;
        b1[kt] = *(const s8v*)(P1 + idx);
        b2[kt] = *(const s8v*)(P2 + idx);
    }
}

// C[32 rows][cols 32w..32w+31] = (A1+A2) @ (B1+B2), 3-product, two acc chains
__device__ __forceinline__ void mfma_pass32(const char* A1s, const char* A2s,
                                            const s8v (&b1)[16], const s8v (&b2)[16],
                                            char* Cb, int w, int l) {
    f16v acca, accb;
#pragma unroll
    for (int i = 0; i < 16; ++i) { acca[i] = 0.f; accb[i] = 0.f; }
#pragma unroll
    for (int kt = 0; kt < 16; ++kt) {
        int off = aoff(l & 31, kt * 32 + (l >> 5) * 16);
        s8v a1 = *(const s8v*)(A1s + off);
        s8v a2 = *(const s8v*)(A2s + off);
        acca = __builtin_amdgcn_mfma_f32_32x32x16_bf16(a1, b1[kt], acca, 0, 0, 0);
        accb = __builtin_amdgcn_mfma_f32_32x32x16_bf16(a2, b1[kt], accb, 0, 0, 0);
        accb = __builtin_amdgcn_mfma_f32_32x32x16_bf16(a1, b2[kt], accb, 0, 0, 0);
    }
    const int col = 32 * w + (l & 31);
#pragma unroll
    for (int reg = 0; reg < 16; ++reg) {
        int row = (reg & 3) + 8 * (reg >> 2) + 4 * (l >> 5);
        *(float*)(Cb + coff(row, 4 * col)) = acca[reg] + accb[reg];
    }
}

__global__ __launch_bounds__(TPB, 2)
void entity_mfma32(const int* __restrict__ prgrph,
                   const unsigned char* __restrict__ pmask8,
                   const int* __restrict__ pmask32,
                   const float* __restrict__ keys,
                   const float* __restrict__ emb,
                   const short* __restrict__ P,       // packed planes: U,V,W x hi,lo
                   float* __restrict__ out,
                   float* __restrict__ enc_ws,        // [B][S][D] f32
                   short* __restrict__ eW_ws)         // [B][S][D] bf16
{
    const int b = blockIdx.x, t = threadIdx.x;
    const int w = t >> 6, l = t & 63;

    __shared__ __align__(16) char lds[65536];
    char* A1s = lds;            // [32][256] bf16 hi plane (swizzled), 16KB
    char* A2s = lds + 16384;    // lo plane, 16KB
    char* Cb  = lds + 32768;    // [32][256] f32 (swizzled), 32KB
    __shared__ unsigned mbits[Sc];

    // ---- mask storage probe (byte-bool vs int32) ----
    int probe;
    { const unsigned char* p = pmask8 + 4 * t; probe = (int)(p[1] | p[2] | p[3]); }
    const bool bytemode = (__syncthreads_or(probe) != 0);

    if (t < Sc) {
        unsigned bits = 0;
        const int base = (b * Sc + t) * Lc;
        if (bytemode) { for (int i = 0; i < Lc; ++i) if (pmask8[base + i])  bits |= 1u << i; }
        else          { for (int i = 0; i < Lc; ++i) if (pmask32[base + i]) bits |= 1u << i; }
        mbits[t] = bits;
    }
    __syncthreads();

    // ---- sentence encodings: 512 threads = 2 sentence-halves x 256 dims ----
    const int* tok_b = prgrph + b * (Sc * Lc);
    float* enc_b = enc_ws + (size_t)b * (Sc * Dc);
    {
        const int d = t & 255, half = t >> 8;
        for (int i = 0; i < 32; ++i) {
            int r = 32 * half + i;
            unsigned bits = mbits[r];
            float acc = 0.f;
            for (int lw = 0; lw < Lc; ++lw)
                if ((bits >> lw) & 1u) acc += emb[(size_t)tok_b[r * Lc + lw] * Dc + d];
            enc_b[r * Dc + d] = acc;
        }
    }
    unsigned long long mask64 = 0;
#pragma unroll 1
    for (int s2 = 0; s2 < Sc; ++s2)
        mask64 |= ((unsigned long long)(mbits[s2] != 0)) << s2;
    __syncthreads();   // enc visible block-wide

    const float* keys_b = keys + (size_t)b * (Kc * Dc);
    short* eW_b = eW_ws + (size_t)b * (Sc * Dc);

    s8v b1[16], b2[16];

    // ---- eW = enc @ W (two 32-sentence passes), W planes in registers ----
    loadB(P + 262144, P + 327680, w, l, b1, b2);
    for (int pass = 0; pass < 2; ++pass) {
#pragma unroll
        for (int r = 0; r < 4; ++r) {
            int row = 4 * w + r, sent = 32 * pass + row;
            f4v ev = *(const f4v*)(enc_b + sent * Dc + 4 * l);
            store_split_row(A1s, A2s, row, l, ev[0], ev[1], ev[2], ev[3]);
        }
        __syncthreads();
        mfma_pass32(A1s, A2s, b1, b2, Cb, w, l);
        __syncthreads();
#pragma unroll
        for (int r = 0; r < 4; ++r) {
            int row = 4 * w + r, sent = 32 * pass + row;
            f4v yv = *(const f4v*)(Cb + coff(row, 16 * l));
            s4v o; o[0] = f2bf(yv[0]); o[1] = f2bf(yv[1]); o[2] = f2bf(yv[2]); o[3] = f2bf(yv[3]);
            *(s4v*)(eW_b + sent * Dc + 4 * l) = o;
        }
        __syncthreads();
    }

    // ---- kv = keys @ V, V planes in registers ----
    loadB(P + 131072, P + 196608, w, l, b1, b2);
#pragma unroll
    for (int r = 0; r < 4; ++r) {
        int row = 4 * w + r;
        f4v kv4 = (row < Kc) ? *(const f4v*)(keys_b + row * Dc + 4 * l)
                             : (f4v){0.f, 0.f, 0.f, 0.f};
        store_split_row(A1s, A2s, row, l, kv4[0], kv4[1], kv4[2], kv4[3]);
    }
    __syncthreads();
    mfma_pass32(A1s, A2s, b1, b2, Cb, w, l);
    __syncthreads();
    f4v kvr[4];
#pragma unroll
    for (int r = 0; r < 4; ++r) {
        int row = 4 * w + r;
        kvr[r] = (row < Kc) ? *(const f4v*)(Cb + coff(row, 16 * l))
                            : (f4v){0.f, 0.f, 0.f, 0.f};
    }
    __syncthreads();

    // ---- zero A planes (h = 0) ----
    {
        s8v z;
#pragma unroll
        for (int i = 0; i < 8; ++i) z[i] = 0;
        *(s8v*)(A1s + t * 32) = z; *(s8v*)(A1s + t * 32 + 16) = z;
        *(s8v*)(A2s + t * 32) = z; *(s8v*)(A2s + t * 32 + 16) = z;
    }
    f4v h[4];
#pragma unroll
    for (int r = 0; r < 4; ++r) h[r] = (f4v){0.f, 0.f, 0.f, 0.f};
    __syncthreads();

    // ---- U planes into registers, then the scan ----
    loadB(P, P + 65536, w, l, b1, b2);

#pragma unroll 1
    for (int s = 0; s < Sc; ++s) {
        if (!((mask64 >> s) & 1ull)) continue;

        // issue e / eW / keys loads early (consumed after MFMA issue)
        f4v e4 = *(const f4v*)(enc_b + s * Dc + 4 * l);
        float ew0, ew1, ew2, ew3;
        { s4v es = *(const s4v*)(eW_b + s * Dc + 4 * l);
          ew0 = bf2f(es[0]); ew1 = bf2f(es[1]); ew2 = bf2f(es[2]); ew3 = bf2f(es[3]); }
        f4v k4[4];
#pragma unroll
        for (int r = 0; r < 4; ++r) {
            int row = 4 * w + r;
            k4[r] = (row < Kc) ? *(const f4v*)(keys_b + row * Dc + 4 * l)
                               : (f4v){0.f, 0.f, 0.f, 0.f};
        }

        mfma_pass32(A1s, A2s, b1, b2, Cb, w, l);   // C = h @ U (h from LDS planes)

        // gate (old h, independent of MFMA result -> overlaps MFMA latency)
        float g[4];
#pragma unroll
        for (int r = 0; r < 4; ++r) {
            int row = 4 * w + r;
            if (row < Kc) {
                float p = e4[0] * (h[r][0] + k4[r][0]) + e4[1] * (h[r][1] + k4[r][1])
                        + e4[2] * (h[r][2] + k4[r][2]) + e4[3] * (h[r][3] + k4[r][3]);
                p = allreduce64(p);
                g[r] = 1.f / (1.f + expf(-p));
            }
        }
        __syncthreads();   // C complete + visible

#pragma unroll
        for (int r = 0; r < 4; ++r) {
            int row = 4 * w + r;
            if (row >= Kc) continue;
            f4v yv = *(const f4v*)(Cb + coff(row, 16 * l));
            float t0 = yv[0] + kvr[r][0] + ew0; t0 = fmaxf(t0, 0.f);
            float t1 = yv[1] + kvr[r][1] + ew1; t1 = fmaxf(t1, 0.f);
            float t2 = yv[2] + kvr[r][2] + ew2; t2 = fmaxf(t2, 0.f);
            float t3 = yv[3] + kvr[r][3] + ew3; t3 = fmaxf(t3, 0.f);
            float u0 = h[r][0] + g[r] * t0;
            float u1 = h[r][1] + g[r] * t1;
            float u2 = h[r][2] + g[r] * t2;
            float u3 = h[r][3] + g[r] * t3;
            float ss = allreduce64(u0 * u0 + u1 * u1 + u2 * u2 + u3 * u3);
            ss = fmaxf(ss, 1e-12f);
            float rs = rsqrtf(ss);
            rs = rs * (1.5f - 0.5f * ss * rs * rs);   // Newton -> ~exact fp32 rsqrt
            u0 *= rs; u1 *= rs; u2 *= rs; u3 *= rs;
            h[r][0] = u0; h[r][1] = u1; h[r][2] = u2; h[r][3] = u3;
            store_split_row(A1s, A2s, row, l, u0, u1, u2, u3);
        }
        __syncthreads();   // h planes updated; C free for next step
    }

    // ---- epilogue ----
    float* out_b = out + (size_t)b * (Kc * Dc);
#pragma unroll
    for (int r = 0; r < 4; ++r) {
        int row = 4 * w + r;
        if (row < Kc) *(f4v*)(out_b + row * Dc + 4 * l) = h[r];
    }
}

extern "C" void kernel_launch(void* const* d_in, const int* in_sizes, int n_in,
                              void* d_out, int out_size, void* d_ws, size_t ws_size,
                              hipStream_t stream) {
    const int*   prgrph = (const int*)d_in[0];
    const void*  pmask  = d_in[1];
    const float* keys   = (const float*)d_in[2];
    const float* emb    = (const float*)d_in[3];
    const float* U      = (const float*)d_in[4];
    const float* V      = (const float*)d_in[5];
    const float* W      = (const float*)d_in[6];

    const int B = in_sizes[2] / (Kc * Dc);   // keys is [B,K,D]

    short* P      = (short*)d_ws;                                   // 6 planes x 65536 bf16 = 768KB
    float* enc_ws = (float*)((char*)d_ws + 786432);                 // B*S*D f32 = 16.8MB
    short* eW_ws  = (short*)((char*)d_ws + 786432 + (size_t)B * Sc * Dc * 4);  // B*S*D bf16 = 8.4MB

    pack32<<<96, 256, 0, stream>>>(U, V, W, P);
    entity_mfma32<<<B, TPB, 0, stream>>>(prgrph,
                                         (const unsigned char*)pmask, (const int*)pmask,
                                         keys, emb, P,
                                         (float*)d_out, enc_ws, eW_ws);
}

// Round 6
// 432.470 us; speedup vs baseline: 7.7767x; 2.0584x over previous
//
#include <hip/hip_runtime.h>
#include <math.h>

// BasicRecurrentEntityEncoder: B=256, S=64, L=16, D=256, K=30
// Round 6 (= round-4 design; r5 failed on non-constant DPP ctrl args):
// split kernels (pack / enc+ek / eW / kv / scan), deferred-norm scan,
// templated DPP wave reductions (VALU pipe), full-width A-plane swizzle.

constexpr int Sc = 64, Lc = 16, Dc = 256, Kc = 30;

typedef short s8v  __attribute__((ext_vector_type(8)));
typedef short s4v  __attribute__((ext_vector_type(4)));
typedef float f4v  __attribute__((ext_vector_type(4)));
typedef float f16v __attribute__((ext_vector_type(16)));

__device__ __forceinline__ short f2bf(float x) {  // RNE float->bf16
    unsigned u = __float_as_uint(x);
    u = u + 0x7FFFu + ((u >> 16) & 1u);
    return (short)(u >> 16);
}
__device__ __forceinline__ float bf2f(short s) {
    return __uint_as_float(((unsigned)(unsigned short)s) << 16);
}

// ---- wave-wide sum on the VALU pipe (DPP), result broadcast via SGPR ----
template <int CTRL, int RMASK>
__device__ __forceinline__ float dpp_add(float v) {
    int t = __builtin_amdgcn_update_dpp(0, __float_as_int(v), CTRL, RMASK, 0xF, true);
    return v + __int_as_float(t);
}
__device__ __forceinline__ float wave_sum(float v) {
    v = dpp_add<0x111, 0xF>(v);   // row_shr:1
    v = dpp_add<0x112, 0xF>(v);   // row_shr:2
    v = dpp_add<0x114, 0xF>(v);   // row_shr:4
    v = dpp_add<0x118, 0xF>(v);   // row_shr:8  -> lane 15 of each row16 has row sum
    v = dpp_add<0x142, 0xA>(v);   // row_bcast15 -> lanes 16-31 / 48-63
    v = dpp_add<0x143, 0xC>(v);   // row_bcast31 -> lanes 32-63 ; lane63 = total
    return __int_as_float(__builtin_amdgcn_readlane(__float_as_int(v), 63));
}

// ---- pack U,V,W into bf16-split planes in 32x32x16 MFMA-B fragment order ----
// P[mat][plane][kt(16)][w(8)][lane(64)][elem(8)]
// logical k = 16*kt + 8*(l>>5) + elem ; logical n (col) = 32*w + (l&31)
__global__ void pack32(const float* __restrict__ U, const float* __restrict__ V,
                       const float* __restrict__ W, short* __restrict__ P) {
    int gid = blockIdx.x * blockDim.x + threadIdx.x;   // 3*16*8*64 = 24576
    int l = gid & 63, w = (gid >> 6) & 7, kt = (gid >> 9) & 15, mat = gid >> 13;
    const float* M = (mat == 0) ? U : ((mat == 1) ? V : W);
    short* P1 = P + (size_t)mat * 131072;
    short* P2 = P1 + 65536;
    int n  = 32 * w + (l & 31);
    int k0 = 16 * kt + 8 * (l >> 5);
    s8v hi, lo;
#pragma unroll
    for (int e = 0; e < 8; ++e) {
        float x = M[(size_t)(k0 + e) * Dc + n];
        short h = f2bf(x);
        hi[e] = h;
        lo[e] = f2bf(x - bf2f(h));
    }
    size_t idx = ((size_t)(kt * 8 + w) * 64 + l) * 8;
    *(s8v*)(P1 + idx) = hi;
    *(s8v*)(P2 + idx) = lo;
}

// swizzled LDS accessors
__device__ __forceinline__ int aoff(int row, int kbyte) { return (row * 512 + kbyte) ^ ((row & 31) << 4); }
__device__ __forceinline__ int coff(int row, int cbyte) { return (row * 1024 + cbyte) ^ ((row & 7) << 4); }

__device__ __forceinline__ void store_split_row(char* A1s, char* A2s, int row, int l,
                                                float x0, float x1, float x2, float x3) {
    s4v hi, lo;
    short h0 = f2bf(x0); hi[0] = h0; lo[0] = f2bf(x0 - bf2f(h0));
    short h1 = f2bf(x1); hi[1] = h1; lo[1] = f2bf(x1 - bf2f(h1));
    short h2 = f2bf(x2); hi[2] = h2; lo[2] = f2bf(x2 - bf2f(h2));
    short h3 = f2bf(x3); hi[3] = h3; lo[3] = f2bf(x3 - bf2f(h3));
    int off = aoff(row, 8 * l);
    *(s4v*)(A1s + off) = hi;
    *(s4v*)(A2s + off) = lo;
}

__device__ __forceinline__ void loadB(const short* __restrict__ P1, const short* __restrict__ P2,
                                      int w, int l, s8v (&b1)[16], s8v (&b2)[16]) {
#pragma unroll
    for (int kt = 0; kt < 16; ++kt) {
        size_t idx = ((size_t)(kt * 8 + w) * 64 + l) * 8;
        b1[kt] = *(const s8v*)(P1 + idx);
        b2[kt] = *(const s8v*)(P2 + idx);
    }
}

// C[32 rows][cols 32w..32w+31] = (A1+A2) @ (B1+B2), 3-product
__device__ __forceinline__ void mfma_pass32(const char* A1s, const char* A2s,
                                            const s8v (&b1)[16], const s8v (&b2)[16],
                                            char* Cb, int w, int l) {
    f16v acc;
#pragma unroll
    for (int i = 0; i < 16; ++i) acc[i] = 0.f;
#pragma unroll
    for (int kt = 0; kt < 16; ++kt) {
        int off = aoff(l & 31, kt * 32 + (l >> 5) * 16);
        s8v a1 = *(const s8v*)(A1s + off);
        s8v a2 = *(const s8v*)(A2s + off);
        acc = __builtin_amdgcn_mfma_f32_32x32x16_bf16(a1, b1[kt], acc, 0, 0, 0);
        acc = __builtin_amdgcn_mfma_f32_32x32x16_bf16(a2, b1[kt], acc, 0, 0, 0);
        acc = __builtin_amdgcn_mfma_f32_32x32x16_bf16(a1, b2[kt], acc, 0, 0, 0);
    }
    const int col = 32 * w + (l & 31);
#pragma unroll
    for (int reg = 0; reg < 16; ++reg) {
        int row = (reg & 3) + 8 * (reg >> 2) + 4 * (l >> 5);
        *(float*)(Cb + coff(row, 4 * col)) = acc[reg];
    }
}

// ---- K1: sentence encodings + ek = enc . keys^T ; one wave per (b,s) ----
__global__ __launch_bounds__(256)
void enc_ek(const int* __restrict__ prgrph,
            const unsigned char* __restrict__ pm8, const int* __restrict__ pm32,
            const float* __restrict__ keys, const float* __restrict__ emb,
            float* __restrict__ enc, float* __restrict__ ek,
            unsigned char* __restrict__ smask) {
    const int t = threadIdx.x, w = t >> 6, l = t & 63;
    int probe;
    { const unsigned char* p = pm8 + 4 * t; probe = (int)(p[1] | p[2] | p[3]); }
    const bool bytemode = (__syncthreads_or(probe) != 0);

    const int sid = blockIdx.x * 4 + w;            // (b,s) id, 0..B*Sc-1
    const int b = sid >> 6;

    int mv = 0;
    if (l < Lc) mv = bytemode ? (int)pm8[(size_t)sid * Lc + l] : pm32[(size_t)sid * Lc + l];
    unsigned long long bal = __ballot(mv != 0);
    const unsigned bits = (unsigned)(bal & 0xFFFFull);
    if (l == 0) smask[sid] = bits ? 1 : 0;

    const int* tb = prgrph + (size_t)sid * Lc;
    f4v acc = {0.f, 0.f, 0.f, 0.f};
#pragma unroll
    for (int i = 0; i < Lc; ++i) {
        int tok = tb[i];
        float m = (float)((bits >> i) & 1u);
        f4v ev = *(const f4v*)(emb + (size_t)tok * Dc + 4 * l);
        acc[0] += m * ev[0]; acc[1] += m * ev[1]; acc[2] += m * ev[2]; acc[3] += m * ev[3];
    }
    *(f4v*)(enc + (size_t)sid * Dc + 4 * l) = acc;

    const float* kb = keys + (size_t)b * Kc * Dc;
    float myek = 0.f;
#pragma unroll
    for (int k = 0; k < Kc; ++k) {
        f4v k4 = *(const f4v*)(kb + (size_t)k * Dc + 4 * l);
        float p = acc[0] * k4[0] + acc[1] * k4[1] + acc[2] * k4[2] + acc[3] * k4[3];
        p = wave_sum(p);
        if (l == k) myek = p;
    }
    if (l < Kc) ek[(size_t)sid * 32 + l] = myek;
}

// ---- K2: eW = enc @ W (one 32-sentence tile per block) ----
__global__ __launch_bounds__(512)
void ew_pass(const float* __restrict__ enc, const short* __restrict__ P,
             float* __restrict__ eW) {
    const int t = threadIdx.x, w = t >> 6, l = t & 63;
    const int b = blockIdx.x >> 1, pass = blockIdx.x & 1;
    __shared__ __align__(16) char lds[65536];
    char* A1s = lds; char* A2s = lds + 16384; char* Cb = lds + 32768;
    s8v b1[16], b2[16];
    loadB(P + 262144, P + 327680, w, l, b1, b2);
    const float* eb = enc + ((size_t)b * Sc + pass * 32) * Dc;
#pragma unroll
    for (int r = 0; r < 4; ++r) {
        int row = 4 * w + r;
        f4v ev = *(const f4v*)(eb + (size_t)row * Dc + 4 * l);
        store_split_row(A1s, A2s, row, l, ev[0], ev[1], ev[2], ev[3]);
    }
    __syncthreads();
    mfma_pass32(A1s, A2s, b1, b2, Cb, w, l);
    __syncthreads();
    float* ob = eW + ((size_t)b * Sc + pass * 32) * Dc;
#pragma unroll
    for (int r = 0; r < 4; ++r) {
        int row = 4 * w + r;
        f4v yv = *(const f4v*)(Cb + coff(row, 16 * l));
        *(f4v*)(ob + (size_t)row * Dc + 4 * l) = yv;
    }
}

// ---- K3: kv = keys @ V ----
__global__ __launch_bounds__(512)
void kv_pass(const float* __restrict__ keys, const short* __restrict__ P,
             float* __restrict__ kvp) {
    const int t = threadIdx.x, w = t >> 6, l = t & 63;
    const int b = blockIdx.x;
    __shared__ __align__(16) char lds[65536];
    char* A1s = lds; char* A2s = lds + 16384; char* Cb = lds + 32768;
    s8v b1[16], b2[16];
    loadB(P + 131072, P + 196608, w, l, b1, b2);
    const float* kb = keys + (size_t)b * Kc * Dc;
#pragma unroll
    for (int r = 0; r < 4; ++r) {
        int row = 4 * w + r;
        f4v k4 = (row < Kc) ? *(const f4v*)(kb + (size_t)row * Dc + 4 * l)
                            : (f4v){0.f, 0.f, 0.f, 0.f};
        store_split_row(A1s, A2s, row, l, k4[0], k4[1], k4[2], k4[3]);
    }
    __syncthreads();
    mfma_pass32(A1s, A2s, b1, b2, Cb, w, l);
    __syncthreads();
    float* ob = kvp + (size_t)b * 32 * Dc;
#pragma unroll
    for (int r = 0; r < 4; ++r) {
        int row = 4 * w + r;
        if (row < Kc) {
            f4v yv = *(const f4v*)(Cb + coff(row, 16 * l));
            *(f4v*)(ob + (size_t)row * Dc + 4 * l) = yv;
        }
    }
}

// ---- K4: the scan (deferred normalization; rs folded as per-row scalar) ----
__global__ __launch_bounds__(512)
void scan_k(const float* __restrict__ enc, const float* __restrict__ eW,
            const float* __restrict__ kvp, const float* __restrict__ ek,
            const unsigned char* __restrict__ smask, const short* __restrict__ P,
            float* __restrict__ out) {
    const int b = blockIdx.x, t = threadIdx.x;
    const int w = t >> 6, l = t & 63;

    __shared__ __align__(16) char lds[65536];
    char* A1s = lds; char* A2s = lds + 16384; char* Cb = lds + 32768;
    __shared__ unsigned char sm[Sc];

    if (t < Sc) sm[t] = smask[(size_t)b * Sc + t];
    // zero A planes (u = 0)
    {
        s8v z;
#pragma unroll
        for (int i = 0; i < 8; ++i) z[i] = 0;
        char* base = lds + t * 64;
#pragma unroll
        for (int i = 0; i < 4; ++i) *(s8v*)(base + 16 * i) = z;
    }

    s8v b1[16], b2[16];
    loadB(P, P + 65536, w, l, b1, b2);   // U planes -> 128 VGPR

    f4v kvr[4];
#pragma unroll
    for (int r = 0; r < 4; ++r) {
        int row = 4 * w + r;
        kvr[r] = (row < Kc) ? *(const f4v*)(kvp + ((size_t)b * 32 + row) * Dc + 4 * l)
                            : (f4v){0.f, 0.f, 0.f, 0.f};
    }
    f4v u[4];
#pragma unroll
    for (int r = 0; r < 4; ++r) u[r] = (f4v){0.f, 0.f, 0.f, 0.f};

    const float* eb  = enc + (size_t)b * Sc * Dc;
    const float* ewb = eW  + (size_t)b * Sc * Dc;
    const float* ekb = ek  + (size_t)b * Sc * 32;
    __syncthreads();

#pragma unroll 1
    for (int s = 0; s < Sc; ++s) {
        if (!sm[s]) continue;

        f4v e4  = *(const f4v*)(eb  + (size_t)s * Dc + 4 * l);
        f4v ew4 = *(const f4v*)(ewb + (size_t)s * Dc + 4 * l);
        float ekr[4];
#pragma unroll
        for (int r = 0; r < 4; ++r) {
            int row = 4 * w + r;
            ekr[r] = (row < Kc) ? ekb[(size_t)s * 32 + row] : 0.f;
        }

        mfma_pass32(A1s, A2s, b1, b2, Cb, w, l);   // y_raw = u_prev @ U

        // deferred finalize of u_prev (DPP reductions overlap MFMA drain):
        float rs[4], g[4];
#pragma unroll
        for (int r = 0; r < 4; ++r) {
            int row = 4 * w + r;
            if (row < Kc) {
                float ssl = u[r][0]*u[r][0] + u[r][1]*u[r][1] + u[r][2]*u[r][2] + u[r][3]*u[r][3];
                float ss = wave_sum(ssl);
                ss = fmaxf(ss, 1e-12f);
                float q = rsqrtf(ss);
                q = q * (1.5f - 0.5f * ss * q * q);     // Newton
                rs[r] = q;
                float eul = e4[0]*u[r][0] + e4[1]*u[r][1] + e4[2]*u[r][2] + e4[3]*u[r][3];
                float eu = wave_sum(eul);
                g[r] = 1.f / (1.f + __expf(-(rs[r] * eu + ekr[r])));
            }
        }
        __syncthreads();   // C ready

#pragma unroll
        for (int r = 0; r < 4; ++r) {
            int row = 4 * w + r;
            if (row >= Kc) continue;
            f4v yv = *(const f4v*)(Cb + coff(row, 16 * l));
            float t0 = fmaxf(rs[r]*yv[0] + kvr[r][0] + ew4[0], 0.f);
            float t1 = fmaxf(rs[r]*yv[1] + kvr[r][1] + ew4[1], 0.f);
            float t2 = fmaxf(rs[r]*yv[2] + kvr[r][2] + ew4[2], 0.f);
            float t3 = fmaxf(rs[r]*yv[3] + kvr[r][3] + ew4[3], 0.f);
            float u0 = rs[r]*u[r][0] + g[r]*t0;
            float u1 = rs[r]*u[r][1] + g[r]*t1;
            float u2 = rs[r]*u[r][2] + g[r]*t2;
            float u3 = rs[r]*u[r][3] + g[r]*t3;
            u[r][0]=u0; u[r][1]=u1; u[r][2]=u2; u[r][3]=u3;
            store_split_row(A1s, A2s, row, l, u0, u1, u2, u3);
        }
        __syncthreads();   // planes updated for next step
    }

    // epilogue: final normalize + write
    float* out_b = out + (size_t)b * (Kc * Dc);
#pragma unroll
    for (int r = 0; r < 4; ++r) {
        int row = 4 * w + r;
        if (row >= Kc) continue;
        float ssl = u[r][0]*u[r][0] + u[r][1]*u[r][1] + u[r][2]*u[r][2] + u[r][3]*u[r][3];
        float ss = wave_sum(ssl);
        ss = fmaxf(ss, 1e-12f);
        float q = rsqrtf(ss);
        q = q * (1.5f - 0.5f * ss * q * q);
        f4v o; o[0]=q*u[r][0]; o[1]=q*u[r][1]; o[2]=q*u[r][2]; o[3]=q*u[r][3];
        *(f4v*)(out_b + (size_t)row * Dc + 4 * l) = o;
    }
}

extern "C" void kernel_launch(void* const* d_in, const int* in_sizes, int n_in,
                              void* d_out, int out_size, void* d_ws, size_t ws_size,
                              hipStream_t stream) {
    const int*   prgrph = (const int*)d_in[0];
    const void*  pmask  = d_in[1];
    const float* keys   = (const float*)d_in[2];
    const float* emb    = (const float*)d_in[3];
    const float* U      = (const float*)d_in[4];
    const float* V      = (const float*)d_in[5];
    const float* W      = (const float*)d_in[6];

    const int B = in_sizes[2] / (Kc * Dc);   // keys is [B,K,D]

    char* ws = (char*)d_ws;
    short* P            = (short*)ws;                              // 768 KB
    float* enc          = (float*)(ws + 786432);                   // B*S*D f32 = 16.78 MB
    float* eW           = (float*)(ws + 786432 + 16777216);        // 16.78 MB
    float* kvp          = (float*)(ws + 786432 + 2*16777216);      // B*32*D f32 = 8.39 MB
    float* ekp          = (float*)(ws + 786432 + 2*16777216 + 8388608);  // B*S*32 = 2.10 MB
    unsigned char* smk  = (unsigned char*)(ws + 786432 + 2*16777216 + 8388608 + 2097152);

    pack32 <<<96, 256, 0, stream>>>(U, V, W, P);
    enc_ek <<<B * Sc / 4, 256, 0, stream>>>(prgrph, (const unsigned char*)pmask,
                                            (const int*)pmask, keys, emb, enc, ekp, smk);
    ew_pass<<<B * 2, 512, 0, stream>>>(enc, P, eW);
    kv_pass<<<B, 512, 0, stream>>>(keys, P, kvp);
    scan_k <<<B, 512, 0, stream>>>(enc, eW, kvp, ekp, smk, P, (float*)d_out);
}